// Round 6
// baseline (270.027 us; speedup 1.0000x reference)
//
#include <hip/hip_runtime.h>
#include <stdint.h>
#include <stddef.h>

#define NN 50000
#define NP 50048            // padded rows (782 * 64) so MFMA A-frag OOB reads stay in-buffer
#define NE 800000
#define NG 128

#define NBKT 256            // dst buckets
#define NPB 196             // nodes per bucket (196*256 = 50176 >= NN)
#define BCAP 4096           // bucket capacity (mean 3136 + 17 sigma)
#define TILE_E 3200         // edges per partition workgroup (250 wgs)

typedef __attribute__((ext_vector_type(8))) short bf16x8;
typedef __attribute__((ext_vector_type(4))) float f32x4;
typedef unsigned short ushort_t;
typedef unsigned int uint_t;

// float -> bf16 (RNE) and bf16x2 unpack helpers
static __device__ inline ushort_t f2b(float f) {
    union { float f; uint_t u; } v; v.f = f;
    uint_t r = v.u + 0x7FFFu + ((v.u >> 16) & 1u);
    return (ushort_t)(r >> 16);
}
static __device__ inline float blo(uint_t u) {
    union { uint_t u; float f; } v; v.u = u << 16; return v.f;
}
static __device__ inline float bhi(uint_t u) {
    union { uint_t u; float f; } v; v.u = u & 0xFFFF0000u; return v.f;
}

// ---------------- cvt + zero fused ----------------
static __global__ void cvt_zero_kernel(const float* __restrict__ x, ushort_t* __restrict__ xb,
                                       int* __restrict__ bucket_cnt, int* __restrict__ cnt,
                                       float* __restrict__ accum) {
    int gid = blockIdx.x * 256 + threadIdx.x;
    if (gid < NBKT) bucket_cnt[gid] = 0;
    if (gid < NG) cnt[gid] = 0;
    if (gid < NG * 64) accum[gid] = 0.f;
    int i = gid * 4;
    if (i + 3 < NN * 96) {
        float4 v = *(const float4*)(x + i);
        ushort_t o0 = f2b(v.x), o1 = f2b(v.y), o2 = f2b(v.z), o3 = f2b(v.w);
        uint_t lo = (uint_t)o0 | ((uint_t)o1 << 16);
        uint_t hi = (uint_t)o2 | ((uint_t)o3 << 16);
        *(uint2*)(xb + i) = make_uint2(lo, hi);
    }
}

// ---------------- bucketed CSR build ----------------
// Phase 1: partition edges into 256 dst-buckets (see R5 notes: kills the 17x
// write amplification of a full-random 4B scatter).
__launch_bounds__(256) static __global__
void partition_kernel(const int* __restrict__ src, const int* __restrict__ dst,
                      int* __restrict__ bucket_cnt, uint_t* __restrict__ part) {
    __shared__ int hist[NBKT];
    int tid = threadIdx.x;
    hist[tid] = 0;
    __syncthreads();
    int base = blockIdx.x * TILE_E;
    uint_t pk[TILE_E / 256 + 1];
    int bk[TILE_E / 256 + 1];
    int cnt = 0;
    for (int i = base + tid; i < base + TILE_E; i += 256) {
        int s = src[i], d = dst[i];
        int b = d / NPB;
        int dl = d - b * NPB;
        pk[cnt] = ((uint_t)dl << 16) | (uint_t)s;
        bk[cnt] = b;
        cnt++;
        atomicAdd(&hist[b], 1);
    }
    __syncthreads();
    int r = atomicAdd(&bucket_cnt[tid], hist[tid]);   // reserve
    __syncthreads();
    hist[tid] = r;                                    // reuse as cursor
    __syncthreads();
    for (int j = 0; j < cnt; j++) {
        int p = atomicAdd(&hist[bk[j]], 1);
        part[bk[j] * BCAP + p] = pk[j];
    }
}

// Phase 2: per-bucket CSR + deg + offs; each block re-scans the 256 bucket
// counts itself (256 x 1KB redundant reads, saves the separate bscan dispatch).
__launch_bounds__(256) static __global__
void csr_build_kernel(const uint_t* __restrict__ part, const int* __restrict__ bucket_cnt,
                      int* __restrict__ deg, int* __restrict__ offs, int* __restrict__ csr) {
    __shared__ uint_t stage[BCAP];
    __shared__ ushort_t cstage[BCAP];
    __shared__ int cnt_s[NBKT];
    __shared__ int scan_l[NBKT];
    __shared__ int cur_l[NBKT];
    int b = blockIdx.x, tid = threadIdx.x;
    // scan bucket counts -> this bucket's global base
    int bc = bucket_cnt[tid];
    cnt_s[tid] = bc;
    scan_l[tid] = bc;
    __syncthreads();
    for (int off = 1; off < NBKT; off <<= 1) {
        int t = (tid >= off) ? scan_l[tid - off] : 0;
        __syncthreads();
        scan_l[tid] += t;
        __syncthreads();
    }
    int base = scan_l[b] - cnt_s[b];
    int n = cnt_s[b];
    __syncthreads();
    // local degree histogram
    cnt_s[tid] = 0;                           // reuse as deg_l
    __syncthreads();
    for (int i = tid; i < n; i += 256) {
        uint_t e = part[(size_t)b * BCAP + i];
        stage[i] = e;
        atomicAdd(&cnt_s[e >> 16], 1);
    }
    __syncthreads();
    int v = cnt_s[tid];
    scan_l[tid] = v;
    __syncthreads();
    for (int off = 1; off < NBKT; off <<= 1) {
        int t = (tid >= off) ? scan_l[tid - off] : 0;
        __syncthreads();
        scan_l[tid] += t;
        __syncthreads();
    }
    int ex = scan_l[tid] - v;                 // exclusive local offset
    scan_l[tid] = ex;
    cur_l[tid] = 0;
    __syncthreads();
    int g = b * NPB + tid;
    if (tid < NPB && g < NN) { deg[g] = v; offs[g] = base + ex; }
    for (int i = tid; i < n; i += 256) {
        uint_t e = stage[i];
        int dl = e >> 16;
        int p = atomicAdd(&cur_l[dl], 1);
        cstage[scan_l[dl] + p] = (ushort_t)(e & 0xFFFFu);
    }
    __syncthreads();
    for (int i = tid; i < n; i += 256) csr[base + i] = (int)cstage[i];
}

// ---------------- MFMA transform: tl = h@Wl.T ; tr = h@Wr.T + b (bf16 in/out, fp32 acc) ----
template <int DOUT, int NT>   // OT = 2*DOUT = NT*16, DIN = 96
__launch_bounds__(256, 4) static __global__
void transform_kernel(const ushort_t* __restrict__ hb, const float* __restrict__ Wl,
                      const float* __restrict__ bias, const float* __restrict__ Wr,
                      ushort_t* __restrict__ tlb, ushort_t* __restrict__ trb) {
    constexpr int DIN = 96;
    __shared__ short w_s[NT * 3 * 64 * 8];
    int tid = threadIdx.x;
    for (int idx = tid; idx < NT * 3 * 64; idx += 256) {
        int ci = idx >> 6, ln = idx & 63;
        int t = ci / 3, s = ci - 3 * t;
        int o = t * 16 + (ln & 15);
        int c0 = s * 32 + (ln >> 4) * 8;
        const float* wrow = (o < DOUT) ? (Wl + (size_t)o * DIN)
                                       : (Wr + (size_t)(o - DOUT) * DIN);
        float4 v0 = *(const float4*)(wrow + c0);
        float4 v1 = *(const float4*)(wrow + c0 + 4);
        bf16x8 pk;
        pk[0] = (short)f2b(v0.x); pk[1] = (short)f2b(v0.y);
        pk[2] = (short)f2b(v0.z); pk[3] = (short)f2b(v0.w);
        pk[4] = (short)f2b(v1.x); pk[5] = (short)f2b(v1.y);
        pk[6] = (short)f2b(v1.z); pk[7] = (short)f2b(v1.w);
        *(bf16x8*)&w_s[idx * 8] = pk;
    }
    int lane = tid & 63;
    int m0 = blockIdx.x * 64 + (tid >> 6) * 16;
    int row = m0 + (lane & 15);
    const bf16x8* arow = (const bf16x8*)(hb + (size_t)row * DIN) + (lane >> 4);
    bf16x8 a0 = arow[0];
    bf16x8 a1 = arow[4];
    bf16x8 a2 = arow[8];
    __syncthreads();
    const bf16x8* wp = (const bf16x8*)w_s + lane;
    f32x4 acc[NT];
#pragma unroll
    for (int t = 0; t < NT; t++) {
        acc[t] = (f32x4){0.f, 0.f, 0.f, 0.f};
        acc[t] = __builtin_amdgcn_mfma_f32_16x16x32_bf16(a0, wp[(t * 3 + 0) * 64], acc[t], 0, 0, 0);
        acc[t] = __builtin_amdgcn_mfma_f32_16x16x32_bf16(a1, wp[(t * 3 + 1) * 64], acc[t], 0, 0, 0);
        acc[t] = __builtin_amdgcn_mfma_f32_16x16x32_bf16(a2, wp[(t * 3 + 2) * 64], acc[t], 0, 0, 0);
    }
    int quad = lane >> 4, col = lane & 15;
#pragma unroll
    for (int t = 0; t < NT; t++) {
        int o = t * 16 + col;
        bool is_r = (o >= DOUT);
        float bv = is_r ? bias[o - DOUT] : 0.f;
        ushort_t* outp = is_r ? trb : tlb;
        int oo = is_r ? (o - DOUT) : o;
#pragma unroll
        for (int r = 0; r < 4; r++) {
            int node = m0 + quad * 4 + r;
            if (node < NN) outp[(size_t)node * DOUT + oo] = f2b(acc[t][r] + bv);
        }
    }
}

// ---------------- aggregation: out = relu?( mean_{j in N(i)} tl[j] + tr[i] ) ----------------
// 16 lanes/node; gather via dwordx4: lanes 0..AL-1 (AL = D/8) each own 16B of
// the bf16 row -> ONE wave VMEM instr per 4 rows (vs 3 with dword gathers),
// 3x fewer vmcnt slots per row. Lanes >= AL dup lane-0's address (same cache
// line as lanes 0-3 -> no extra traffic). fp32 acc, 8 feats/lane.
template <int D, bool RELU, bool OUT_BF16>
static __global__ void agg2_kernel(const ushort_t* __restrict__ tlb, const ushort_t* __restrict__ trb,
                                   const int* __restrict__ offs, const int* __restrict__ deg,
                                   const int* __restrict__ csr, void* __restrict__ outv) {
    constexpr int RD = D / 2;   // dwords per row
    constexpr int AL = D / 8;   // active lanes (12 for D=96, 8 for D=64)
    int gtid = blockIdx.x * 256 + threadIdx.x;
    int node = gtid >> 4;
    int lane = threadIdx.x & 15;
    if (node >= NN) return;
    int ll = (lane < AL) ? lane : 0;
    int off = offs[node], dg = deg[node];
    const uint_t* tl32 = (const uint_t*)tlb;
    float acc[8];
#pragma unroll
    for (int q = 0; q < 8; q++) acc[q] = 0.f;
    int k = 0;
    for (; k + 4 <= dg; k += 4) {
        int i0 = csr[off + k + 0];
        int i1 = csr[off + k + 1];
        int i2 = csr[off + k + 2];
        int i3 = csr[off + k + 3];
        uint4 a0 = *(const uint4*)(tl32 + (size_t)i0 * RD + 4 * ll);
        uint4 a1 = *(const uint4*)(tl32 + (size_t)i1 * RD + 4 * ll);
        uint4 a2 = *(const uint4*)(tl32 + (size_t)i2 * RD + 4 * ll);
        uint4 a3 = *(const uint4*)(tl32 + (size_t)i3 * RD + 4 * ll);
        acc[0] += (blo(a0.x) + blo(a1.x)) + (blo(a2.x) + blo(a3.x));
        acc[1] += (bhi(a0.x) + bhi(a1.x)) + (bhi(a2.x) + bhi(a3.x));
        acc[2] += (blo(a0.y) + blo(a1.y)) + (blo(a2.y) + blo(a3.y));
        acc[3] += (bhi(a0.y) + bhi(a1.y)) + (bhi(a2.y) + bhi(a3.y));
        acc[4] += (blo(a0.z) + blo(a1.z)) + (blo(a2.z) + blo(a3.z));
        acc[5] += (bhi(a0.z) + bhi(a1.z)) + (bhi(a2.z) + bhi(a3.z));
        acc[6] += (blo(a0.w) + blo(a1.w)) + (blo(a2.w) + blo(a3.w));
        acc[7] += (bhi(a0.w) + bhi(a1.w)) + (bhi(a2.w) + bhi(a3.w));
    }
    for (; k < dg; k++) {
        uint4 a0 = *(const uint4*)(tl32 + (size_t)csr[off + k] * RD + 4 * ll);
        acc[0] += blo(a0.x); acc[1] += bhi(a0.x);
        acc[2] += blo(a0.y); acc[3] += bhi(a0.y);
        acc[4] += blo(a0.z); acc[5] += bhi(a0.z);
        acc[6] += blo(a0.w); acc[7] += bhi(a0.w);
    }
    float s = 1.f / (float)max(dg, 1);
    uint4 t = *(const uint4*)((const uint_t*)trb + (size_t)node * RD + 4 * ll);
    float v0 = fmaf(acc[0], s, blo(t.x));
    float v1 = fmaf(acc[1], s, bhi(t.x));
    float v2 = fmaf(acc[2], s, blo(t.y));
    float v3 = fmaf(acc[3], s, bhi(t.y));
    float v4 = fmaf(acc[4], s, blo(t.z));
    float v5 = fmaf(acc[5], s, bhi(t.z));
    float v6 = fmaf(acc[6], s, blo(t.w));
    float v7 = fmaf(acc[7], s, bhi(t.w));
    if (RELU) {
        v0 = fmaxf(v0, 0.f); v1 = fmaxf(v1, 0.f); v2 = fmaxf(v2, 0.f); v3 = fmaxf(v3, 0.f);
        v4 = fmaxf(v4, 0.f); v5 = fmaxf(v5, 0.f); v6 = fmaxf(v6, 0.f); v7 = fmaxf(v7, 0.f);
    }
    if (lane < AL) {
        if (OUT_BF16) {
            uint4 o;
            o.x = (uint_t)f2b(v0) | ((uint_t)f2b(v1) << 16);
            o.y = (uint_t)f2b(v2) | ((uint_t)f2b(v3) << 16);
            o.z = (uint_t)f2b(v4) | ((uint_t)f2b(v5) << 16);
            o.w = (uint_t)f2b(v6) | ((uint_t)f2b(v7) << 16);
            *(uint4*)((uint_t*)outv + (size_t)node * RD + 4 * lane) = o;
        } else {
            float* op = (float*)outv + (size_t)node * D + 8 * lane;
            *(float4*)op = make_float4(v0, v1, v2, v3);
            *(float4*)(op + 4) = make_float4(v4, v5, v6, v7);
        }
    }
}

// ---------------- pooling over sorted batch ids (fp32 H) ----------------
static __global__ void pool_kernel(const float* __restrict__ h, const int* __restrict__ batch,
                                   float* __restrict__ accum, int* __restrict__ cnt) {
    int per = (NN + gridDim.x - 1) / gridDim.x;
    int start = blockIdx.x * per;
    int end = min(start + per, NN);
    if (start >= end) return;
    int c = threadIdx.x;                         // 64 features
    int gcur = batch[start];
    float acc = 0.f;
    int count = 0;
    for (int i = start; i < end; i++) {
        int g = batch[i];
        if (g != gcur) {
            atomicAdd(&accum[gcur * 64 + c], acc);
            if (c == 0) atomicAdd(&cnt[gcur], count);
            acc = 0.f; count = 0; gcur = g;
        }
        acc += h[(size_t)i * 64 + c];
        count++;
    }
    atomicAdd(&accum[gcur * 64 + c], acc);
    if (c == 0) atomicAdd(&cnt[gcur], count);
}

static __global__ void finalize_kernel(const float* __restrict__ accum, const int* __restrict__ cnt,
                                       float* __restrict__ out) {
    int i = blockIdx.x * 256 + threadIdx.x;
    if (i < NG * 64) {
        int g = i >> 6;
        out[i] = accum[i] / (float)max(cnt[g], 1);
    }
}

// ---------------- launch ----------------
extern "C" void kernel_launch(void* const* d_in, const int* in_sizes, int n_in,
                              void* d_out, int out_size, void* d_ws, size_t ws_size,
                              hipStream_t stream) {
    (void)in_sizes; (void)n_in; (void)out_size; (void)ws_size;
    const float* x   = (const float*)d_in[0];
    const int*   ei  = (const int*)d_in[1];
    const int*   bat = (const int*)d_in[2];
    const float* Wl0 = (const float*)d_in[3];
    const float* b0  = (const float*)d_in[4];
    const float* Wr0 = (const float*)d_in[5];
    const float* Wl1 = (const float*)d_in[6];
    const float* b1  = (const float*)d_in[7];
    const float* Wr1 = (const float*)d_in[8];
    const float* Wl2 = (const float*)d_in[9];
    const float* b2  = (const float*)d_in[10];
    const float* Wr2 = (const float*)d_in[11];
    float* out = (float*)d_out;
    const int* src = ei;
    const int* dst = ei + NE;

    char* p = (char*)d_ws;
    auto carve = [&](size_t bytes) -> char* {
        char* r = p;
        p += (bytes + 255) & ~(size_t)255;
        return r;
    };
    int*      deg    = (int*)carve((size_t)NN * 4);
    int*      offs   = (int*)carve((size_t)NN * 4);
    int*      bucket_cnt = (int*)carve(NBKT * 4);
    uint_t*   part   = (uint_t*)carve((size_t)NBKT * BCAP * 4);
    int*      csr    = (int*)carve((size_t)NE * 4);
    int*      cnt    = (int*)carve(NG * 4);
    float*    accum  = (float*)carve((size_t)NG * 64 * 4);
    ushort_t* xb     = (ushort_t*)carve((size_t)NP * 96 * 2);   // layer-0 input; reused as h2b
    ushort_t* h1b    = (ushort_t*)carve((size_t)NP * 96 * 2);
    ushort_t* tlb    = (ushort_t*)carve((size_t)NP * 96 * 2);
    ushort_t* trb    = (ushort_t*)carve((size_t)NP * 96 * 2);
    float*    Hf     = (float*)carve((size_t)NN * 64 * 4);

    dim3 b256(256);
    cvt_zero_kernel<<<dim3((NN * 96 / 4 + 255) / 256), b256, 0, stream>>>(x, xb, bucket_cnt, cnt, accum);

    partition_kernel<<<dim3(NE / TILE_E), b256, 0, stream>>>(src, dst, bucket_cnt, part);
    csr_build_kernel<<<dim3(NBKT), b256, 0, stream>>>(part, bucket_cnt, deg, offs, csr);

    dim3 tGrid(NP / 64);                       // 782
    dim3 aGrid(NN * 16 / 256);                 // 3125

    // layer 0: 96 -> 96, relu
    transform_kernel<96, 12><<<tGrid, b256, 0, stream>>>(xb, Wl0, b0, Wr0, tlb, trb);
    agg2_kernel<96, true, true><<<aGrid, b256, 0, stream>>>(tlb, trb, offs, deg, csr, h1b);
    // layer 1: 96 -> 96, relu  (h2b reuses xb)
    transform_kernel<96, 12><<<tGrid, b256, 0, stream>>>(h1b, Wl1, b1, Wr1, tlb, trb);
    agg2_kernel<96, true, true><<<aGrid, b256, 0, stream>>>(tlb, trb, offs, deg, csr, xb);
    // layer 2: 96 -> 64, no relu, fp32 out for pooling
    transform_kernel<64, 8><<<tGrid, b256, 0, stream>>>(xb, Wl2, b2, Wr2, tlb, trb);
    agg2_kernel<64, false, false><<<aGrid, b256, 0, stream>>>(tlb, trb, offs, deg, csr, Hf);

    pool_kernel<<<dim3(512), dim3(64), 0, stream>>>(Hf, bat, accum, cnt);
    finalize_kernel<<<dim3((NG * 64 + 255) / 256), b256, 0, stream>>>(accum, cnt, out);
}

// Round 7
// 261.301 us; speedup vs baseline: 1.0334x; 1.0334x over previous
//
#include <hip/hip_runtime.h>
#include <stdint.h>
#include <stddef.h>

#define NN 50000
#define NP 50048            // padded rows (782 * 64) so MFMA A-frag OOB reads stay in-buffer
#define NE 800000
#define NG 128

#define NBKT 256            // dst buckets
#define NPB 196             // nodes per bucket (196*256 = 50176 >= NN)
#define BCAP 4096           // bucket capacity (mean ~3125 + 17 sigma)
#define TILE_E 3072         // edges per partition workgroup (uniform 12 iters/thread)
#define AGB 3125            // agg blocks per chunk (3125 * 16 nodes = 50000)

typedef __attribute__((ext_vector_type(8))) short bf16x8;
typedef __attribute__((ext_vector_type(4))) float f32x4;
typedef unsigned short ushort_t;
typedef unsigned int uint_t;

// float -> bf16 (RNE) and bf16x2 unpack helpers
static __device__ inline ushort_t f2b(float f) {
    union { float f; uint_t u; } v; v.f = f;
    uint_t r = v.u + 0x7FFFu + ((v.u >> 16) & 1u);
    return (ushort_t)(r >> 16);
}
static __device__ inline float blo(uint_t u) {
    union { uint_t u; float f; } v; v.u = u << 16; return v.f;
}
static __device__ inline float bhi(uint_t u) {
    union { uint_t u; float f; } v; v.u = u & 0xFFFF0000u; return v.f;
}

// ---------------- cvt + zero fused ----------------
static __global__ void cvt_zero_kernel(const float* __restrict__ x, ushort_t* __restrict__ xb,
                                       int* __restrict__ bucket_cnt, int* __restrict__ cnt,
                                       float* __restrict__ accum) {
    int gid = blockIdx.x * 256 + threadIdx.x;
    if (gid < NBKT) bucket_cnt[gid] = 0;
    if (gid < NG) cnt[gid] = 0;
    if (gid < NG * 64) accum[gid] = 0.f;
    int i = gid * 4;
    if (i + 3 < NN * 96) {
        float4 v = *(const float4*)(x + i);
        ushort_t o0 = f2b(v.x), o1 = f2b(v.y), o2 = f2b(v.z), o3 = f2b(v.w);
        uint_t lo = (uint_t)o0 | ((uint_t)o1 << 16);
        uint_t hi = (uint_t)o2 | ((uint_t)o3 << 16);
        *(uint2*)(xb + i) = make_uint2(lo, hi);
    }
}

// ---------------- bucketed CSR build ----------------
// Phase 1: two-pass partition (no per-thread arrays -> no scratch spill; R6
// version's pk[13]/bk[13] with non-uniform trip count lived in HBM scratch).
// Edge data read twice (2 x 6.4 MB, trivial); scatter runs are per-wg
// contiguous inside bucket regions (kills the 17x write amplification, R5).
__launch_bounds__(256) static __global__
void partition_kernel(const int* __restrict__ src, const int* __restrict__ dst,
                      int* __restrict__ bucket_cnt, uint_t* __restrict__ part) {
    __shared__ int hist[NBKT];
    int tid = threadIdx.x;
    hist[tid] = 0;
    __syncthreads();
    int base = blockIdx.x * TILE_E;
    int end = min(base + TILE_E, NE);
    for (int i = base + tid; i < end; i += 256)
        atomicAdd(&hist[dst[i] / NPB], 1);
    __syncthreads();
    int r = atomicAdd(&bucket_cnt[tid], hist[tid]);   // reserve
    __syncthreads();
    hist[tid] = r;                                    // reuse as cursor
    __syncthreads();
    for (int i = base + tid; i < end; i += 256) {
        int s = src[i], d = dst[i];
        int b = d / NPB;
        int dl = d - b * NPB;
        int p = atomicAdd(&hist[b], 1);
        part[b * BCAP + p] = ((uint_t)dl << 16) | (uint_t)s;
    }
}

// Phase 2: per-bucket CSR + deg + offs; each block re-scans the 256 bucket
// counts itself (saves the separate bscan dispatch).
__launch_bounds__(256) static __global__
void csr_build_kernel(const uint_t* __restrict__ part, const int* __restrict__ bucket_cnt,
                      int* __restrict__ deg, int* __restrict__ offs, int* __restrict__ csr) {
    __shared__ uint_t stage[BCAP];
    __shared__ ushort_t cstage[BCAP];
    __shared__ int cnt_s[NBKT];
    __shared__ int scan_l[NBKT];
    __shared__ int cur_l[NBKT];
    int b = blockIdx.x, tid = threadIdx.x;
    int bc = bucket_cnt[tid];
    cnt_s[tid] = bc;
    scan_l[tid] = bc;
    __syncthreads();
    for (int off = 1; off < NBKT; off <<= 1) {
        int t = (tid >= off) ? scan_l[tid - off] : 0;
        __syncthreads();
        scan_l[tid] += t;
        __syncthreads();
    }
    int base = scan_l[b] - cnt_s[b];
    int n = cnt_s[b];
    __syncthreads();
    cnt_s[tid] = 0;                           // reuse as deg_l
    __syncthreads();
    for (int i = tid; i < n; i += 256) {
        uint_t e = part[(size_t)b * BCAP + i];
        stage[i] = e;
        atomicAdd(&cnt_s[e >> 16], 1);
    }
    __syncthreads();
    int v = cnt_s[tid];
    scan_l[tid] = v;
    __syncthreads();
    for (int off = 1; off < NBKT; off <<= 1) {
        int t = (tid >= off) ? scan_l[tid - off] : 0;
        __syncthreads();
        scan_l[tid] += t;
        __syncthreads();
    }
    int ex = scan_l[tid] - v;
    scan_l[tid] = ex;
    cur_l[tid] = 0;
    __syncthreads();
    int g = b * NPB + tid;
    if (tid < NPB && g < NN) { deg[g] = v; offs[g] = base + ex; }
    for (int i = tid; i < n; i += 256) {
        uint_t e = stage[i];
        int dl = e >> 16;
        int p = atomicAdd(&cur_l[dl], 1);
        cstage[scan_l[dl] + p] = (ushort_t)(e & 0xFFFFu);
    }
    __syncthreads();
    for (int i = tid; i < n; i += 256) csr[base + i] = (int)cstage[i];
}

// ---------------- MFMA transform: tl = h@Wl.T ; tr = h@Wr.T + b (bf16, fp32 acc) ----
// Outputs written CHUNK-MAJOR: tlc[(c*NN + node)*32 + f], c = o>>5, f = o&31.
// Each 3.2 MB chunk fits a per-XCD L2 -> agg gathers become L2 hits.
template <int DOUT, int NT>   // OT = 2*DOUT = NT*16, DIN = 96
__launch_bounds__(256, 4) static __global__
void transform_kernel(const ushort_t* __restrict__ hb, const float* __restrict__ Wl,
                      const float* __restrict__ bias, const float* __restrict__ Wr,
                      ushort_t* __restrict__ tlc, ushort_t* __restrict__ trc) {
    constexpr int DIN = 96;
    __shared__ short w_s[NT * 3 * 64 * 8];
    int tid = threadIdx.x;
    for (int idx = tid; idx < NT * 3 * 64; idx += 256) {
        int ci = idx >> 6, ln = idx & 63;
        int t = ci / 3, s = ci - 3 * t;
        int o = t * 16 + (ln & 15);
        int c0 = s * 32 + (ln >> 4) * 8;
        const float* wrow = (o < DOUT) ? (Wl + (size_t)o * DIN)
                                       : (Wr + (size_t)(o - DOUT) * DIN);
        float4 v0 = *(const float4*)(wrow + c0);
        float4 v1 = *(const float4*)(wrow + c0 + 4);
        bf16x8 pk;
        pk[0] = (short)f2b(v0.x); pk[1] = (short)f2b(v0.y);
        pk[2] = (short)f2b(v0.z); pk[3] = (short)f2b(v0.w);
        pk[4] = (short)f2b(v1.x); pk[5] = (short)f2b(v1.y);
        pk[6] = (short)f2b(v1.z); pk[7] = (short)f2b(v1.w);
        *(bf16x8*)&w_s[idx * 8] = pk;
    }
    int lane = tid & 63;
    int m0 = blockIdx.x * 64 + (tid >> 6) * 16;
    int row = m0 + (lane & 15);
    const bf16x8* arow = (const bf16x8*)(hb + (size_t)row * DIN) + (lane >> 4);
    bf16x8 a0 = arow[0];
    bf16x8 a1 = arow[4];
    bf16x8 a2 = arow[8];
    __syncthreads();
    const bf16x8* wp = (const bf16x8*)w_s + lane;
    f32x4 acc[NT];
#pragma unroll
    for (int t = 0; t < NT; t++) {
        acc[t] = (f32x4){0.f, 0.f, 0.f, 0.f};
        acc[t] = __builtin_amdgcn_mfma_f32_16x16x32_bf16(a0, wp[(t * 3 + 0) * 64], acc[t], 0, 0, 0);
        acc[t] = __builtin_amdgcn_mfma_f32_16x16x32_bf16(a1, wp[(t * 3 + 1) * 64], acc[t], 0, 0, 0);
        acc[t] = __builtin_amdgcn_mfma_f32_16x16x32_bf16(a2, wp[(t * 3 + 2) * 64], acc[t], 0, 0, 0);
    }
    int quad = lane >> 4, col = lane & 15;
#pragma unroll
    for (int t = 0; t < NT; t++) {
        int o = t * 16 + col;
        bool is_r = (o >= DOUT);
        float bv = is_r ? bias[o - DOUT] : 0.f;
        ushort_t* outp = is_r ? trc : tlc;
        int oo = is_r ? (o - DOUT) : o;
        int cch = oo >> 5, f = oo & 31;
        ushort_t* ob = outp + ((size_t)cch * NN) * 32 + f;
#pragma unroll
        for (int r = 0; r < 4; r++) {
            int node = m0 + quad * 4 + r;
            if (node < NN) ob[(size_t)node * 32] = f2b(acc[t][r] + bv);
        }
    }
}

// ---------------- chunked aggregation ----------------
// out = relu?( mean_{j in N(i)} tl[j] + tr[i] ), one 32-feature chunk per
// grid segment (chunk = blockIdx.x / AGB): gather array = 3.2 MB -> L2-resident.
// 16 lanes/node = 4 neighbor-groups x 4 feature-lanes; lane loads one dwordx4
// (4 lanes cover the 64B row = 1 cache line); unroll 8 -> 8 rows in flight per
// node; shfl_xor(4,8) reduces across neighbor groups at the end.
template <int D, bool RELU, bool OUT_BF16>
__launch_bounds__(256) static __global__
void agg3_kernel(const ushort_t* __restrict__ tlc, const ushort_t* __restrict__ trc,
                 const int* __restrict__ offs, const int* __restrict__ deg,
                 const int* __restrict__ csr, void* __restrict__ outv) {
    int bx = blockIdx.x;
    int c = bx / AGB;
    int b = bx - c * AGB;
    int tid = threadIdx.x;
    int node = b * 16 + (tid >> 4);
    int lane = tid & 15;
    int ng = lane >> 2, fl = lane & 3;
    const uint_t* tl = (const uint_t*)tlc + (size_t)c * NN * 16;
    int off = offs[node], dg = deg[node];
    float acc[8];
#pragma unroll
    for (int q = 0; q < 8; q++) acc[q] = 0.f;
    int k = 0;
    for (; k + 8 <= dg; k += 8) {
        int s0 = csr[off + k + ng];
        int s1 = csr[off + k + 4 + ng];
        uint4 a0 = *(const uint4*)(tl + (size_t)s0 * 16 + 4 * fl);
        uint4 a1 = *(const uint4*)(tl + (size_t)s1 * 16 + 4 * fl);
        acc[0] += blo(a0.x) + blo(a1.x); acc[1] += bhi(a0.x) + bhi(a1.x);
        acc[2] += blo(a0.y) + blo(a1.y); acc[3] += bhi(a0.y) + bhi(a1.y);
        acc[4] += blo(a0.z) + blo(a1.z); acc[5] += bhi(a0.z) + bhi(a1.z);
        acc[6] += blo(a0.w) + blo(a1.w); acc[7] += bhi(a0.w) + bhi(a1.w);
    }
    if (k + 4 <= dg) {
        int s0 = csr[off + k + ng];
        uint4 a0 = *(const uint4*)(tl + (size_t)s0 * 16 + 4 * fl);
        acc[0] += blo(a0.x); acc[1] += bhi(a0.x);
        acc[2] += blo(a0.y); acc[3] += bhi(a0.y);
        acc[4] += blo(a0.z); acc[5] += bhi(a0.z);
        acc[6] += blo(a0.w); acc[7] += bhi(a0.w);
        k += 4;
    }
    if (ng < dg - k) {
        int s0 = csr[off + k + ng];
        uint4 a0 = *(const uint4*)(tl + (size_t)s0 * 16 + 4 * fl);
        acc[0] += blo(a0.x); acc[1] += bhi(a0.x);
        acc[2] += blo(a0.y); acc[3] += bhi(a0.y);
        acc[4] += blo(a0.z); acc[5] += bhi(a0.z);
        acc[6] += blo(a0.w); acc[7] += bhi(a0.w);
    }
    // reduce across the 4 neighbor groups (lane^4, lane^8 stay in the 16-lane node group)
#pragma unroll
    for (int q = 0; q < 8; q++) {
        acc[q] += __shfl_xor(acc[q], 4, 64);
        acc[q] += __shfl_xor(acc[q], 8, 64);
    }
    float s = 1.f / (float)max(dg, 1);
    uint4 t = *(const uint4*)((const uint_t*)trc + (size_t)c * NN * 16 + (size_t)node * 16 + 4 * fl);
    float v0 = fmaf(acc[0], s, blo(t.x));
    float v1 = fmaf(acc[1], s, bhi(t.x));
    float v2 = fmaf(acc[2], s, blo(t.y));
    float v3 = fmaf(acc[3], s, bhi(t.y));
    float v4 = fmaf(acc[4], s, blo(t.z));
    float v5 = fmaf(acc[5], s, bhi(t.z));
    float v6 = fmaf(acc[6], s, blo(t.w));
    float v7 = fmaf(acc[7], s, bhi(t.w));
    if (RELU) {
        v0 = fmaxf(v0, 0.f); v1 = fmaxf(v1, 0.f); v2 = fmaxf(v2, 0.f); v3 = fmaxf(v3, 0.f);
        v4 = fmaxf(v4, 0.f); v5 = fmaxf(v5, 0.f); v6 = fmaxf(v6, 0.f); v7 = fmaxf(v7, 0.f);
    }
    if (ng == 0) {
        if (OUT_BF16) {
            // next-layer input layout: [node][96] bf16 (row = D/2 dwords)
            uint4 o;
            o.x = (uint_t)f2b(v0) | ((uint_t)f2b(v1) << 16);
            o.y = (uint_t)f2b(v2) | ((uint_t)f2b(v3) << 16);
            o.z = (uint_t)f2b(v4) | ((uint_t)f2b(v5) << 16);
            o.w = (uint_t)f2b(v6) | ((uint_t)f2b(v7) << 16);
            *(uint4*)((uint_t*)outv + (size_t)node * (D / 2) + c * 16 + 4 * fl) = o;
        } else {
            float* op = (float*)outv + (size_t)node * D + c * 32 + 8 * fl;
            *(float4*)op = make_float4(v0, v1, v2, v3);
            *(float4*)(op + 4) = make_float4(v4, v5, v6, v7);
        }
    }
}

// ---------------- pooling over sorted batch ids (fp32 H) ----------------
static __global__ void pool_kernel(const float* __restrict__ h, const int* __restrict__ batch,
                                   float* __restrict__ accum, int* __restrict__ cnt) {
    int per = (NN + gridDim.x - 1) / gridDim.x;
    int start = blockIdx.x * per;
    int end = min(start + per, NN);
    if (start >= end) return;
    int c = threadIdx.x;                         // 64 features
    int gcur = batch[start];
    float acc = 0.f;
    int count = 0;
    for (int i = start; i < end; i++) {
        int g = batch[i];
        if (g != gcur) {
            atomicAdd(&accum[gcur * 64 + c], acc);
            if (c == 0) atomicAdd(&cnt[gcur], count);
            acc = 0.f; count = 0; gcur = g;
        }
        acc += h[(size_t)i * 64 + c];
        count++;
    }
    atomicAdd(&accum[gcur * 64 + c], acc);
    if (c == 0) atomicAdd(&cnt[gcur], count);
}

static __global__ void finalize_kernel(const float* __restrict__ accum, const int* __restrict__ cnt,
                                       float* __restrict__ out) {
    int i = blockIdx.x * 256 + threadIdx.x;
    if (i < NG * 64) {
        int g = i >> 6;
        out[i] = accum[i] / (float)max(cnt[g], 1);
    }
}

// ---------------- launch ----------------
extern "C" void kernel_launch(void* const* d_in, const int* in_sizes, int n_in,
                              void* d_out, int out_size, void* d_ws, size_t ws_size,
                              hipStream_t stream) {
    (void)in_sizes; (void)n_in; (void)out_size; (void)ws_size;
    const float* x   = (const float*)d_in[0];
    const int*   ei  = (const int*)d_in[1];
    const int*   bat = (const int*)d_in[2];
    const float* Wl0 = (const float*)d_in[3];
    const float* b0  = (const float*)d_in[4];
    const float* Wr0 = (const float*)d_in[5];
    const float* Wl1 = (const float*)d_in[6];
    const float* b1  = (const float*)d_in[7];
    const float* Wr1 = (const float*)d_in[8];
    const float* Wl2 = (const float*)d_in[9];
    const float* b2  = (const float*)d_in[10];
    const float* Wr2 = (const float*)d_in[11];
    float* out = (float*)d_out;
    const int* src = ei;
    const int* dst = ei + NE;

    char* p = (char*)d_ws;
    auto carve = [&](size_t bytes) -> char* {
        char* r = p;
        p += (bytes + 255) & ~(size_t)255;
        return r;
    };
    int*      deg    = (int*)carve((size_t)NN * 4);
    int*      offs   = (int*)carve((size_t)NN * 4);
    int*      bucket_cnt = (int*)carve(NBKT * 4);
    uint_t*   part   = (uint_t*)carve((size_t)NBKT * BCAP * 4);
    int*      csr    = (int*)carve((size_t)NE * 4);
    int*      cnt    = (int*)carve(NG * 4);
    float*    accum  = (float*)carve((size_t)NG * 64 * 4);
    ushort_t* xb     = (ushort_t*)carve((size_t)NP * 96 * 2);   // layer-0 input; reused as h2b
    ushort_t* h1b    = (ushort_t*)carve((size_t)NP * 96 * 2);
    ushort_t* tlc    = (ushort_t*)carve((size_t)3 * NN * 32 * 2);  // chunk-major
    ushort_t* trc    = (ushort_t*)carve((size_t)3 * NN * 32 * 2);  // chunk-major
    float*    Hf     = (float*)carve((size_t)NN * 64 * 4);

    dim3 b256(256);
    cvt_zero_kernel<<<dim3((NN * 96 / 4 + 255) / 256), b256, 0, stream>>>(x, xb, bucket_cnt, cnt, accum);

    partition_kernel<<<dim3((NE + TILE_E - 1) / TILE_E), b256, 0, stream>>>(src, dst, bucket_cnt, part);
    csr_build_kernel<<<dim3(NBKT), b256, 0, stream>>>(part, bucket_cnt, deg, offs, csr);

    dim3 tGrid(NP / 64);                       // 782

    // layer 0: 96 -> 96, relu
    transform_kernel<96, 12><<<tGrid, b256, 0, stream>>>(xb, Wl0, b0, Wr0, tlc, trc);
    agg3_kernel<96, true, true><<<dim3(3 * AGB), b256, 0, stream>>>(tlc, trc, offs, deg, csr, h1b);
    // layer 1: 96 -> 96, relu  (h2b reuses xb)
    transform_kernel<96, 12><<<tGrid, b256, 0, stream>>>(h1b, Wl1, b1, Wr1, tlc, trc);
    agg3_kernel<96, true, true><<<dim3(3 * AGB), b256, 0, stream>>>(tlc, trc, offs, deg, csr, xb);
    // layer 2: 96 -> 64, no relu, fp32 out for pooling
    transform_kernel<64, 8><<<tGrid, b256, 0, stream>>>(xb, Wl2, b2, Wr2, tlc, trc);
    agg3_kernel<64, false, false><<<dim3(2 * AGB), b256, 0, stream>>>(tlc, trc, offs, deg, csr, Hf);

    pool_kernel<<<dim3(1024), dim3(64), 0, stream>>>(Hf, bat, accum, cnt);
    finalize_kernel<<<dim3((NG * 64 + 255) / 256), b256, 0, stream>>>(accum, cnt, out);
}